// Round 1
// baseline (470.435 us; speedup 1.0000x reference)
//
#include <hip/hip_runtime.h>

#define DIM 64
#define BN_EPS 1e-5f

// ---------------- degree: deg[dst[e]] += 1 ----------------
__global__ void k_degree(const int* __restrict__ dst, int* __restrict__ deg, int E) {
    int e = blockIdx.x * blockDim.x + threadIdx.x;
    if (e < E) atomicAdd(&deg[dst[e]], 1);
}

// ---------------- dinv[i] = rsqrt(deg[i] + 1)  (self-loop) ----------------
__global__ void k_dinv(const int* __restrict__ deg, float* __restrict__ dinv, int N) {
    int i = blockIdx.x * blockDim.x + threadIdx.x;
    if (i < N) dinv[i] = rsqrtf((float)deg[i] + 1.0f);
}

// ---------------- h = x @ W ; wave-per-row, lane = out feature ----------------
__global__ void k_gemm(const float* __restrict__ x, const float* __restrict__ W,
                       float* __restrict__ h, int N) {
    __shared__ float Wl[DIM * DIM];
    for (int i = threadIdx.x; i < DIM * DIM; i += blockDim.x) Wl[i] = W[i];
    __syncthreads();
    const int lane = threadIdx.x & 63;
    const int wave = threadIdx.x >> 6;
    const int wpb  = blockDim.x >> 6;
    for (int r = blockIdx.x * wpb + wave; r < N; r += gridDim.x * wpb) {
        float xr  = x[r * DIM + lane];
        float acc = 0.f;
#pragma unroll
        for (int k = 0; k < DIM; ++k) {
            float xk = __shfl(xr, k, 64);
            acc += xk * Wl[k * DIM + lane];
        }
        h[r * DIM + lane] = acc;
    }
}

// ---------------- scatter: agg[dst] += h[src] * dinv[src]*dinv[dst] ----------------
// one wave per edge, lane = feature -> coalesced 256B row read + coalesced atomics
__global__ void k_scatter(const int* __restrict__ src, const int* __restrict__ dst,
                          const float* __restrict__ dinv, const float* __restrict__ h,
                          float* __restrict__ agg, int E) {
    int lane = threadIdx.x & 63;
    int e = blockIdx.x * (blockDim.x >> 6) + (threadIdx.x >> 6);
    if (e >= E) return;
    int s = src[e], d = dst[e];
    float norm = dinv[s] * dinv[d];
    float v = h[(size_t)s * DIM + lane] * norm;
    atomicAdd(&agg[(size_t)d * DIM + lane], v);
}

// ---------------- bn pass 1: a = relu(agg + h*dinv^2 + b) (self-loop fused),
// store a in-place into agg, accumulate per-feature sum/sumsq ----------------
__global__ void k_bn1(const float* __restrict__ h, const float* __restrict__ dinv,
                      const float* __restrict__ b, float* __restrict__ agg,
                      float* __restrict__ gsum, float* __restrict__ gsumsq, int N) {
    __shared__ float s1[256], s2[256];
    const int lane = threadIdx.x & 63;
    const int wave = threadIdx.x >> 6;
    float bf = b[lane];
    float lsum = 0.f, lsq = 0.f;
    for (int r = blockIdx.x * 4 + wave; r < N; r += gridDim.x * 4) {
        float di = dinv[r];
        size_t idx = (size_t)r * DIM + lane;
        float a = agg[idx] + h[idx] * di * di + bf;
        a = fmaxf(a, 0.f);
        agg[idx] = a;
        lsum += a;
        lsq  += a * a;
    }
    s1[threadIdx.x] = lsum;
    s2[threadIdx.x] = lsq;
    __syncthreads();
    if (threadIdx.x < 64) {
        float t1 = s1[threadIdx.x] + s1[threadIdx.x + 64] + s1[threadIdx.x + 128] + s1[threadIdx.x + 192];
        float t2 = s2[threadIdx.x] + s2[threadIdx.x + 64] + s2[threadIdx.x + 128] + s2[threadIdx.x + 192];
        atomicAdd(&gsum[threadIdx.x], t1);
        atomicAdd(&gsumsq[threadIdx.x], t2);
    }
}

// ---------------- finalize per-feature scale/shift ----------------
__global__ void k_stats(const float* __restrict__ gsum, const float* __restrict__ gsumsq,
                        const float* __restrict__ gamma, const float* __restrict__ beta,
                        float* __restrict__ scale, float* __restrict__ shift, int N) {
    int f = threadIdx.x;
    if (f < DIM) {
        float inv_n = 1.0f / (float)N;
        float mean = gsum[f] * inv_n;
        float var  = gsumsq[f] * inv_n - mean * mean;
        float istd = rsqrtf(var + BN_EPS);
        float sc = gamma[f] * istd;
        scale[f] = sc;
        shift[f] = beta[f] - mean * sc;
    }
}

// ---------------- bn pass 2: out = a*scale + shift (in-place on d_out) ----------------
__global__ void k_bn2(float* __restrict__ a, const float* __restrict__ scale,
                      const float* __restrict__ shift, long total) {
    long i = (long)blockIdx.x * blockDim.x + threadIdx.x;
    long stride = (long)gridDim.x * blockDim.x;
    for (; i < total; i += stride) {
        int f = (int)(i & 63);
        a[i] = a[i] * scale[f] + shift[f];
    }
}

extern "C" void kernel_launch(void* const* d_in, const int* in_sizes, int n_in,
                              void* d_out, int out_size, void* d_ws, size_t ws_size,
                              hipStream_t stream) {
    const float* x     = (const float*)d_in[0];
    const int*   ei    = (const int*)d_in[1];
    const float* W     = (const float*)d_in[2];
    const float* b     = (const float*)d_in[3];
    const float* gamma = (const float*)d_in[4];
    const float* beta  = (const float*)d_in[5];
    float* out = (float*)d_out;

    const int N = in_sizes[0] / DIM;    // 100000
    const int E = in_sizes[1] / 2;      // 1000000
    const int* esrc = ei;               // edge_index[0]
    const int* edst = ei + E;           // edge_index[1]

    // workspace layout (bytes): deg[N] | dinv[N] | h[N*64] | stats[256 floats]
    char* ws = (char*)d_ws;
    size_t off = 0;
    int*   deg  = (int*)(ws + off);   off += (size_t)N * sizeof(int);
    off = (off + 255) & ~(size_t)255;
    float* dinv = (float*)(ws + off); off += (size_t)N * sizeof(float);
    off = (off + 255) & ~(size_t)255;
    float* h    = (float*)(ws + off); off += (size_t)N * DIM * sizeof(float);
    off = (off + 255) & ~(size_t)255;
    float* gsum   = (float*)(ws + off);
    float* gsumsq = gsum + 64;
    float* scale  = gsum + 128;
    float* shift  = gsum + 192;

    // agg / relu activations live in d_out (saves 25.6 MB of ws; bn2 is in-place)
    float* agg = out;

    hipMemsetAsync(deg, 0, (size_t)N * sizeof(int), stream);
    hipMemsetAsync(agg, 0, (size_t)N * DIM * sizeof(float), stream);
    hipMemsetAsync(gsum, 0, 256 * sizeof(float), stream);

    k_degree<<<(E + 255) / 256, 256, 0, stream>>>(edst, deg, E);
    k_dinv<<<(N + 255) / 256, 256, 0, stream>>>(deg, dinv, N);
    k_gemm<<<1024, 256, 0, stream>>>(x, W, h, N);
    k_scatter<<<(E + 3) / 4, 256, 0, stream>>>(esrc, edst, dinv, h, agg, E);
    k_bn1<<<1024, 256, 0, stream>>>(h, dinv, b, agg, gsum, gsumsq, N);
    k_stats<<<1, 64, 0, stream>>>(gsum, gsumsq, gamma, beta, scale, shift, N);
    k_bn2<<<2048, 256, 0, stream>>>(agg, scale, shift, (long)N * DIM);
}

// Round 2
// 352.385 us; speedup vs baseline: 1.3350x; 1.3350x over previous
//
#include <hip/hip_runtime.h>

#define DIM 64
#define BN_EPS 1e-5f

// ---------------- degree: deg[dst[e]] += 1 ----------------
__global__ void k_degree(const int* __restrict__ dst, int* __restrict__ deg, int E) {
    int e = blockIdx.x * blockDim.x + threadIdx.x;
    if (e < E) atomicAdd(&deg[dst[e]], 1);
}

// ---------------- dinv[i] = rsqrt(deg[i] + 1)  (self-loop) ----------------
__global__ void k_dinv(const int* __restrict__ deg, float* __restrict__ dinv, int N) {
    int i = blockIdx.x * blockDim.x + threadIdx.x;
    if (i < N) dinv[i] = rsqrtf((float)deg[i] + 1.0f);
}

// ---------------- scan stage 1: per-block exclusive scan + block sums ----------------
__global__ void k_scan1(const int* __restrict__ deg, int* __restrict__ rowptr,
                        int* __restrict__ bsum, int N) {
    __shared__ int s[256];
    int i = blockIdx.x * 256 + threadIdx.x;
    int v = (i < N) ? deg[i] : 0;
    s[threadIdx.x] = v;
    __syncthreads();
    for (int off = 1; off < 256; off <<= 1) {
        int t = (threadIdx.x >= off) ? s[threadIdx.x - off] : 0;
        __syncthreads();
        s[threadIdx.x] += t;
        __syncthreads();
    }
    if (i < N) rowptr[i] = s[threadIdx.x] - v;  // exclusive
    if (threadIdx.x == 255) bsum[blockIdx.x] = s[255];
}

// ---------------- scan stage 2: scan block sums (single block, nb <= 512) ----------------
__global__ void k_scan2(const int* __restrict__ bsum, int* __restrict__ bofs,
                        int nb, int* __restrict__ rowptr, int N) {
    __shared__ int s[512];
    int v = ((int)threadIdx.x < nb) ? bsum[threadIdx.x] : 0;
    s[threadIdx.x] = v;
    __syncthreads();
    for (int off = 1; off < 512; off <<= 1) {
        int t = (threadIdx.x >= (unsigned)off) ? s[threadIdx.x - off] : 0;
        __syncthreads();
        s[threadIdx.x] += t;
        __syncthreads();
    }
    if ((int)threadIdx.x < nb) bofs[threadIdx.x] = s[threadIdx.x] - v;
    if ((int)threadIdx.x == nb - 1) rowptr[N] = s[threadIdx.x];  // total = E
}

// ---------------- scan stage 3: add block offsets ----------------
__global__ void k_scan3(int* __restrict__ rowptr, const int* __restrict__ bofs, int N) {
    int i = blockIdx.x * 256 + threadIdx.x;
    if (i < N) rowptr[i] += bofs[blockIdx.x];
}

// ---------------- bucket: counting-sort edges by dst ----------------
__global__ void k_bucket(const int* __restrict__ src, const int* __restrict__ dst,
                         const int* __restrict__ rowptr, int* __restrict__ cursor,
                         int* __restrict__ ssrc, int E) {
    int e = blockIdx.x * blockDim.x + threadIdx.x;
    if (e < E) {
        int d = dst[e];
        int p = atomicAdd(&cursor[d], 1);
        ssrc[rowptr[d] + p] = src[e];
    }
}

// ---------------- h = x @ W : row per thread, W broadcast from LDS ----------------
__global__ __launch_bounds__(256) void k_gemm(const float* __restrict__ x,
                                              const float* __restrict__ W,
                                              float* __restrict__ h, int N) {
    __shared__ float Wl[DIM * DIM];
    for (int i = threadIdx.x; i < DIM * DIM; i += 256) Wl[i] = W[i];
    __syncthreads();
    int r = blockIdx.x * 256 + threadIdx.x;
    if (r >= N) return;
    const float4* xr4 = (const float4*)(x + (size_t)r * DIM);
    float4 acc[16];
#pragma unroll
    for (int j = 0; j < 16; ++j) acc[j] = make_float4(0.f, 0.f, 0.f, 0.f);
    for (int k0 = 0; k0 < 16; ++k0) {
        float4 xv = xr4[k0];
#pragma unroll
        for (int kk = 0; kk < 4; ++kk) {
            float xs = (&xv.x)[kk];
            const float4* wrow = (const float4*)(Wl + (k0 * 4 + kk) * DIM);
#pragma unroll
            for (int j = 0; j < 16; ++j) {
                float4 w = wrow[j];
                acc[j].x += xs * w.x;
                acc[j].y += xs * w.y;
                acc[j].z += xs * w.z;
                acc[j].w += xs * w.w;
            }
        }
    }
    float4* hr = (float4*)(h + (size_t)r * DIM);
#pragma unroll
    for (int j = 0; j < 16; ++j) hr[j] = acc[j];
}

// ---------------- pull-aggregate + bias + self-loop + relu + BN partial sums ----------------
// wave per node (grid-stride), lane = feature
__global__ __launch_bounds__(256) void k_aggregate(
        const int* __restrict__ rowptr, const int* __restrict__ ssrc,
        const float* __restrict__ dinv, const float* __restrict__ h,
        const float* __restrict__ b, float* __restrict__ out,
        float* __restrict__ gsum, float* __restrict__ gsumsq, int N) {
    __shared__ float s1[256], s2[256];
    const int lane = threadIdx.x & 63;
    const int wave = threadIdx.x >> 6;
    const float bf = b[lane];
    float lsum = 0.f, lsq = 0.f;
    for (int d = blockIdx.x * 4 + wave; d < N; d += gridDim.x * 4) {
        int beg = rowptr[d], end = rowptr[d + 1];
        float dd = dinv[d];
        float a0 = 0.f, a1 = 0.f, a2 = 0.f, a3 = 0.f;
        int i = beg;
        for (; i + 3 < end; i += 4) {
            int s0 = ssrc[i], sA = ssrc[i + 1], sB = ssrc[i + 2], sC = ssrc[i + 3];
            a0 += h[(size_t)s0 * DIM + lane] * dinv[s0];
            a1 += h[(size_t)sA * DIM + lane] * dinv[sA];
            a2 += h[(size_t)sB * DIM + lane] * dinv[sB];
            a3 += h[(size_t)sC * DIM + lane] * dinv[sC];
        }
        for (; i < end; ++i) {
            int s0 = ssrc[i];
            a0 += h[(size_t)s0 * DIM + lane] * dinv[s0];
        }
        size_t di = (size_t)d * DIM + lane;
        float a = ((a0 + a1) + (a2 + a3)) * dd + h[di] * dd * dd + bf;
        a = fmaxf(a, 0.f);
        out[di] = a;
        lsum += a;
        lsq += a * a;
    }
    s1[threadIdx.x] = lsum;
    s2[threadIdx.x] = lsq;
    __syncthreads();
    if (threadIdx.x < 64) {
        float t1 = s1[threadIdx.x] + s1[threadIdx.x + 64] + s1[threadIdx.x + 128] + s1[threadIdx.x + 192];
        float t2 = s2[threadIdx.x] + s2[threadIdx.x + 64] + s2[threadIdx.x + 128] + s2[threadIdx.x + 192];
        atomicAdd(&gsum[threadIdx.x], t1);
        atomicAdd(&gsumsq[threadIdx.x], t2);
    }
}

// ---------------- finalize per-feature scale/shift ----------------
__global__ void k_stats(const float* __restrict__ gsum, const float* __restrict__ gsumsq,
                        const float* __restrict__ gamma, const float* __restrict__ beta,
                        float* __restrict__ scale, float* __restrict__ shift, int N) {
    int f = threadIdx.x;
    if (f < DIM) {
        float inv_n = 1.0f / (float)N;
        float mean = gsum[f] * inv_n;
        float var = gsumsq[f] * inv_n - mean * mean;
        float istd = rsqrtf(var + BN_EPS);
        float sc = gamma[f] * istd;
        scale[f] = sc;
        shift[f] = beta[f] - mean * sc;
    }
}

// ---------------- bn pass 2: out = a*scale + shift (in-place) ----------------
__global__ void k_bn2(float* __restrict__ a, const float* __restrict__ scale,
                      const float* __restrict__ shift, long total) {
    long i = (long)blockIdx.x * blockDim.x + threadIdx.x;
    long stride = (long)gridDim.x * blockDim.x;
    for (; i < total; i += stride) {
        int f = (int)(i & 63);
        a[i] = a[i] * scale[f] + shift[f];
    }
}

extern "C" void kernel_launch(void* const* d_in, const int* in_sizes, int n_in,
                              void* d_out, int out_size, void* d_ws, size_t ws_size,
                              hipStream_t stream) {
    const float* x     = (const float*)d_in[0];
    const int*   ei    = (const int*)d_in[1];
    const float* W     = (const float*)d_in[2];
    const float* b     = (const float*)d_in[3];
    const float* gamma = (const float*)d_in[4];
    const float* beta  = (const float*)d_in[5];
    float* out = (float*)d_out;

    const int N = in_sizes[0] / DIM;  // 100000
    const int E = in_sizes[1] / 2;    // 1000000
    const int* esrc = ei;
    const int* edst = ei + E;
    const int NB = (N + 255) / 256;   // 391 scan blocks

    // workspace layout
    char* ws = (char*)d_ws;
    size_t off = 0;
    int* deg = (int*)(ws + off);     off += (size_t)N * sizeof(int);          // also reused as cursor
    off = (off + 255) & ~(size_t)255;
    float* dinv = (float*)(ws + off); off += (size_t)N * sizeof(float);
    off = (off + 255) & ~(size_t)255;
    int* rowptr = (int*)(ws + off);  off += (size_t)(N + 1) * sizeof(int);
    off = (off + 255) & ~(size_t)255;
    int* bsum = (int*)(ws + off);    off += (size_t)NB * sizeof(int);
    off = (off + 255) & ~(size_t)255;
    int* bofs = (int*)(ws + off);    off += (size_t)NB * sizeof(int);
    off = (off + 255) & ~(size_t)255;
    int* ssrc = (int*)(ws + off);    off += (size_t)E * sizeof(int);
    off = (off + 255) & ~(size_t)255;
    float* h = (float*)(ws + off);   off += (size_t)N * DIM * sizeof(float);
    off = (off + 255) & ~(size_t)255;
    float* gsum   = (float*)(ws + off);
    float* gsumsq = gsum + 64;
    float* scale  = gsum + 128;
    float* shift  = gsum + 192;

    hipMemsetAsync(deg, 0, (size_t)N * sizeof(int), stream);
    hipMemsetAsync(gsum, 0, 256 * sizeof(float), stream);

    k_degree<<<(E + 255) / 256, 256, 0, stream>>>(edst, deg, E);
    k_dinv<<<NB, 256, 0, stream>>>(deg, dinv, N);
    k_scan1<<<NB, 256, 0, stream>>>(deg, rowptr, bsum, N);
    k_scan2<<<1, 512, 0, stream>>>(bsum, bofs, NB, rowptr, N);
    k_scan3<<<NB, 256, 0, stream>>>(rowptr, bofs, N);
    // reuse deg as bucket cursor
    hipMemsetAsync(deg, 0, (size_t)N * sizeof(int), stream);
    k_bucket<<<(E + 255) / 256, 256, 0, stream>>>(esrc, edst, rowptr, deg, ssrc, E);
    k_gemm<<<NB, 256, 0, stream>>>(x, W, h, N);
    k_aggregate<<<1024, 256, 0, stream>>>(rowptr, ssrc, dinv, h, b, out, gsum, gsumsq, N);
    k_stats<<<1, 64, 0, stream>>>(gsum, gsumsq, gamma, beta, scale, shift, N);
    k_bn2<<<2048, 256, 0, stream>>>(out, scale, shift, (long)N * DIM);
}